// Round 1
// baseline (257.156 us; speedup 1.0000x reference)
//
#include <hip/hip_runtime.h>

#define NA 1000
#define ND 513
#define IMG 512
#define CROP 362
#define TOP ((IMG - CROP) / 2)          // 75
#define NPIX (CROP * CROP)              // 131044
#define NB 8

// Static device buffers: avoids dependence on ws_size, rewritten every call
// (deterministic). g_yT layout: [group(2)][angle(1000)][det(513)][4 floats]
// so the 4 batch values of one group at one (angle, det) are a single float4.
__device__ float2 g_tab[NA];
__device__ float  g_yT[(size_t)2 * NA * ND * 4];

// cos/sin table scaled by 1/delta_s, computed in double for precision.
__global__ void table_kernel() {
    int a = blockIdx.x * blockDim.x + threadIdx.x;
    if (a >= NA) return;
    double th = (double)a * (3.14159265358979323846 / (double)NA);
    // reference divides by f32(2*0.13/512); fold the reciprocal into the table
    float delta_f = (float)(2.0 * 0.13 / (double)(ND - 1));
    double inv = 1.0 / (double)delta_f;
    g_tab[a] = make_float2((float)(cos(th) * inv), (float)(sin(th) * inv));
}

// x[b][a][d] (b-major) -> g_yT[g][a][d][4]  (batch-innermost, split in 2 groups)
__global__ void transpose_kernel(const float* __restrict__ x) {
    int t = blockIdx.x * blockDim.x + threadIdx.x;   // t = a*ND + d
    if (t >= NA * ND) return;
    const int S = NA * ND;
    float4 lo = make_float4(x[0 * S + t], x[1 * S + t], x[2 * S + t], x[3 * S + t]);
    float4 hi = make_float4(x[4 * S + t], x[5 * S + t], x[6 * S + t], x[7 * S + t]);
    ((float4*)g_yT)[t]       = lo;
    ((float4*)g_yT)[S + t]   = hi;
}

// One thread = one output pixel x one batch-group(4). Loop over 1000 angles.
// out[b,0,i,j] = acc[b, TOP+j, TOP+i] * pi/NA  => X from i, Y from j.
__launch_bounds__(256)
__global__ void bp_kernel(float* __restrict__ out) {
    __shared__ float2 s_tab[NA];
    for (int t = threadIdx.x; t < NA; t += 256) s_tab[t] = g_tab[t];
    __syncthreads();

    int pix = blockIdx.x * 256 + threadIdx.x;
    if (pix >= NPIX) return;
    int g = blockIdx.y;                 // batch group 0..1
    int i = pix / CROP;                 // output row  -> X
    int j = pix - i * CROP;             // output col  -> Y (contiguous lanes)

    const float step = (float)(0.26 / 511.0);
    float X = fmaf((float)(TOP + i), step, -0.13f);
    float Y = fmaf((float)(TOP + j), step, -0.13f);

    const float4* __restrict__ src = ((const float4*)g_yT) + (size_t)g * (NA * ND);

    float4 acc = make_float4(0.f, 0.f, 0.f, 0.f);
    // For crop pixels p in [0.23, 511.77] => i0 in [0,511], i1 in [1,512]:
    // always in-bounds (margin ~0.2 cells >> fp error) -> no clamps needed.
    for (int a = 0; a < NA; ++a) {
        float2 cs = s_tab[a];
        float p  = fmaf(X, cs.x, fmaf(Y, cs.y, 256.0f));
        float fi = floorf(p);
        float w  = p - fi;
        int   i0 = (int)fi;
        const float4* ptr = src + (a * ND + i0);
        float4 v0 = ptr[0];
        float4 v1 = ptr[1];
        float w0 = 1.0f - w;
        acc.x = fmaf(v0.x, w0, fmaf(v1.x, w, acc.x));
        acc.y = fmaf(v0.y, w0, fmaf(v1.y, w, acc.y));
        acc.z = fmaf(v0.z, w0, fmaf(v1.z, w, acc.z));
        acc.w = fmaf(v0.w, w0, fmaf(v1.w, w, acc.w));
    }

    const float scale = (float)(3.14159265358979323846 / 1000.0);
    int ob = g * 4;
    out[(size_t)(ob + 0) * NPIX + pix] = acc.x * scale;
    out[(size_t)(ob + 1) * NPIX + pix] = acc.y * scale;
    out[(size_t)(ob + 2) * NPIX + pix] = acc.z * scale;
    out[(size_t)(ob + 3) * NPIX + pix] = acc.w * scale;
}

extern "C" void kernel_launch(void* const* d_in, const int* in_sizes, int n_in,
                              void* d_out, int out_size, void* d_ws, size_t ws_size,
                              hipStream_t stream) {
    const float* x = (const float*)d_in[0];
    float* out = (float*)d_out;

    table_kernel<<<(NA + 255) / 256, 256, 0, stream>>>();
    transpose_kernel<<<(NA * ND + 255) / 256, 256, 0, stream>>>(x);

    dim3 grid((NPIX + 255) / 256, 2);
    bp_kernel<<<grid, 256, 0, stream>>>(out);
}